// Round 4
// baseline (3295.366 us; speedup 1.0000x reference)
//
#include <hip/hip_runtime.h>
#include <hip/hip_bf16.h>

typedef __hip_bfloat16 bf16;

#define Hd 320
#define Wd 640
#define HWP (Hd*Wd)      // 204800
#define Bn 2
#define NCH1 188
#define HID 48
#define NBHW (Bn*HWP)    // 409600

static __device__ __forceinline__ float b2f(bf16 v){ return __bfloat162float(v); }
static __device__ __forceinline__ bf16  f2b(float v){ return __float2bfloat16(v); }

// templated external-buffer load/store
template<typename T> static __device__ __forceinline__ float ld(const T* p, long i);
template<> __device__ __forceinline__ float ld<bf16>(const bf16* p, long i){ return b2f(p[i]); }
template<> __device__ __forceinline__ float ld<float>(const float* p, long i){ return p[i]; }
template<typename T> static __device__ __forceinline__ void stv(T* p, long i, float v);
template<> __device__ __forceinline__ void stv<bf16>(bf16* p, long i, float v){ p[i] = f2b(v); }
template<> __device__ __forceinline__ void stv<float>(float* p, long i, float v){ p[i] = v; }
template<typename T> struct want_flag;           // 0 = bf16, 1 = f32
template<> struct want_flag<bf16>  { static const int v = 0; };
template<> struct want_flag<float> { static const int v = 1; };

// ---------------- dtype probe: even-index low-halves of d as bf16 ----------------
// bf16 buffer: those are real d values in [0,64] -> ~0 out-of-range.
// f32 buffer: those are mantissa bits -> ~50% out-of-range/NaN.
__global__ void probe_k(const unsigned short* __restrict__ dq, int* __restrict__ flag)
{
  __shared__ int cnt;
  if (threadIdx.x == 0) cnt = 0;
  __syncthreads();
  int bad = 0;
  for (int i = threadIdx.x; i < 2048; i += 256) {
    unsigned int bits = ((unsigned int)dq[2*i]) << 16;
    float v = __uint_as_float(bits);
    if (!(fabsf(v) <= 65.f)) bad++;          // NaN also counts
  }
  atomicAdd(&cnt, bad);
  __syncthreads();
  if (threadIdx.x == 0) *flag = (cnt > 64) ? 1 : 0;
}

// ---------------- weight conversion: T OIHW -> f32 [c][oc][9] (+heads) ----------------
template<typename T>
__global__ void wconv_k(const int* __restrict__ flag,
                        const T* __restrict__ c1, const T* __restrict__ c2,
                        const T* __restrict__ c3,
                        const T* __restrict__ hdw, const T* __restrict__ hdb,
                        const T* __restrict__ hsxw, const T* __restrict__ hsxb,
                        const T* __restrict__ hsyw, const T* __restrict__ hsyb,
                        const T* __restrict__ hcw,  const T* __restrict__ hcb,
                        const T* __restrict__ hfw,  const T* __restrict__ hfb,
                        float* __restrict__ wf1, float* __restrict__ wf2,
                        float* __restrict__ wf3, float* __restrict__ wh,
                        float* __restrict__ bh)
{
  if (*flag != want_flag<T>::v) return;
  int stride = gridDim.x * blockDim.x;
  int t0 = blockIdx.x * blockDim.x + threadIdx.x;
  for (int i = t0; i < HID*NCH1*9; i += stride) {
    int oc = i / (NCH1*9); int rem = i - oc*(NCH1*9);
    int c = rem / 9; int k = rem - c*9;
    wf1[(c*HID + oc)*9 + k] = ld(c1, i);
  }
  for (int i = t0; i < HID*HID*9; i += stride) {
    int oc = i / (HID*9); int rem = i - oc*(HID*9);
    int c = rem / 9; int k = rem - c*9;
    wf2[(c*HID + oc)*9 + k] = ld(c2, i);
    wf3[(c*HID + oc)*9 + k] = ld(c3, i);
  }
  for (int i = t0; i < HID; i += stride) {
    wh[0*HID + i] = ld(hdw, i);
    wh[1*HID + i] = ld(hsxw, i);
    wh[2*HID + i] = ld(hsyw, i);
    wh[3*HID + i] = ld(hcw, i);
  }
  for (int i = t0; i < 16*HID; i += stride) wh[4*HID + i] = ld(hfw, i);
  if (t0 == 0) {
    bh[0] = ld(hdb,0); bh[1] = ld(hsxb,0); bh[2] = ld(hsyb,0); bh[3] = ld(hcb,0);
    for (int j = 0; j < 16; ++j) bh[4+j] = ld(hfb, j);
  }
}

// GN-stats epilogue: per-(b,g) sum & sumsq of the f32 accumulators
static __device__ __forceinline__ void gn_epilogue(
    const float* acc, float (*sred)[2], float* st, int b, int tid)
{
  int lane = tid & 63;
  #pragma unroll
  for (int g = 0; g < 8; ++g) {
    float s = 0.f, s2 = 0.f;
    #pragma unroll
    for (int j = 0; j < 6; ++j) { float v = acc[g*6+j]; s += v; s2 += v*v; }
    #pragma unroll
    for (int off = 32; off > 0; off >>= 1) {
      s  += __shfl_xor(s,  off);
      s2 += __shfl_xor(s2, off);
    }
    if (lane == 0) { atomicAdd(&sred[g][0], s); atomicAdd(&sred[g][1], s2); }
  }
  __syncthreads();
  if (tid < 16) atomicAdd(&st[(b*8 + (tid>>1))*2 + (tid&1)], sred[tid>>1][tid&1]);
}

// ---------------- conv1 fused: warp+corr computed in staging; one batch ----------------
template<typename T>
__global__ __launch_bounds__(256) void conv1f_k(
    const int* __restrict__ flag, int b,
    const T* __restrict__ fL, const T* __restrict__ fR, const T* __restrict__ feat,
    const T* __restrict__ dP, const T* __restrict__ sxP, const T* __restrict__ syP,
    const T* __restrict__ confP, const float* __restrict__ wf,
    bf16* __restrict__ out48, float* __restrict__ st)
{
  if (*flag != want_flag<T>::v) return;
  __shared__ float tile[4][342];    // 18 rows x pitch 19
  __shared__ float dtile[18][18];
  __shared__ float sred[8][2];
  int x0 = blockIdx.x * 16, y0 = blockIdx.y * 16;
  int tid = threadIdx.x;
  int tx = tid & 15, ty = tid >> 4;
  if (tid < 16) ((float*)sred)[tid] = 0.f;
  const T* fLb = fL + (long)b*64*HWP;
  const T* fRb = fR + (long)b*64*HWP;
  // stage d halo tile
  for (int i = tid; i < 324; i += 256) {
    int r = i / 18, cl = i - r*18;
    int gy = y0 - 1 + r, gx = x0 - 1 + cl;
    float dv = 0.f;
    if (gy >= 0 && gy < Hd && gx >= 0 && gx < Wd)
      dv = ld(dP, (long)b*HWP + (long)gy*Wd + gx);
    dtile[r][cl] = dv;
  }
  float acc[HID];
  #pragma unroll
  for (int i = 0; i < HID; ++i) acc[i] = 0.f;
  for (int c0 = 0; c0 < NCH1; c0 += 4) {
    __syncthreads();
    for (int i = tid; i < 4*324; i += 256) {
      int cc = i / 324; int rem = i - cc*324;
      int r = rem / 18; int cl = rem - r*18;
      int gy = y0 - 1 + r, gx = x0 - 1 + cl;
      float v = 0.f;
      if (gy >= 0 && gy < Hd && gx >= 0 && gx < Wd) {
        int c = c0 + cc;
        long rowb = (long)gy*Wd;
        if (c < 64) {
          v = ld(fLb, (long)c*HWP + rowb + gx);
        } else if (c < 128) {            // fR warped by d
          float pos = fminf(fmaxf((float)gx - dtile[r][cl], 0.f), (float)(Wd-1));
          float x0f = floorf(pos); float w = pos - x0f;
          int i0 = (int)x0f; int i1 = min(i0+1, Wd-1);
          const T* p = fRb + (long)(c-64)*HWP + rowb;
          v = ld(p, i0)*(1.f-w) + ld(p, i1)*w;
        } else if (c < 144) {
          v = ld(feat, ((long)(b*16 + c-128))*HWP + rowb + gx);
        } else if (c == 144) {
          v = dtile[r][cl];
        } else if (c == 145) {
          v = ld(sxP, (long)b*HWP + rowb + gx);
        } else if (c == 146) {
          v = ld(syP, (long)b*HWP + rowb + gx);
        } else if (c == 147) {
          v = ld(confP, (long)b*HWP + rowb + gx);
        } else {                         // cost: c2 = g*5 + i5
          int c2 = c - 148; int g = c2 / 5; int i5 = c2 - g*5;
          float pos = fminf(fmaxf((float)gx - dtile[r][cl] - (float)(i5-2), 0.f), (float)(Wd-1));
          float x0f = floorf(pos); float w = pos - x0f;
          int i0 = (int)x0f; int i1 = min(i0+1, Wd-1);
          float a = 0.f;
          #pragma unroll
          for (int cc8 = 0; cc8 < 8; ++cc8) {
            int ch = g*8 + cc8;
            const T* p = fRb + (long)ch*HWP + rowb;
            float fr = ld(p, i0)*(1.f-w) + ld(p, i1)*w;
            a += ld(fLb, (long)ch*HWP + rowb + gx) * fr;
          }
          v = a * 0.125f;
        }
      }
      tile[cc][r*19 + cl] = v;
    }
    __syncthreads();
    #pragma unroll
    for (int cc = 0; cc < 4; ++cc) {
      float v[9];
      #pragma unroll
      for (int dr = 0; dr < 3; ++dr)
        #pragma unroll
        for (int dc = 0; dc < 3; ++dc)
          v[dr*3+dc] = tile[cc][(ty+dr)*19 + (tx+dc)];
      const float* wp = wf + (long)(c0+cc)*HID*9;   // wave-uniform -> scalar loads
      #pragma unroll
      for (int oc = 0; oc < HID; ++oc) {
        float a = acc[oc];
        #pragma unroll
        for (int k = 0; k < 9; ++k) a += wp[oc*9+k] * v[k];
        acc[oc] = a;
      }
    }
  }
  long obase = (long)(y0+ty)*Wd + (x0+tx);
  #pragma unroll
  for (int oc = 0; oc < HID; ++oc) out48[obase + (long)oc*HWP] = f2b(acc[oc]);
  gn_epilogue(acc, sred, st, b, tid);
}

// ---------------- convH: 48->48, GN+SiLU fused on input; one batch ----------------
template<typename T>
__global__ __launch_bounds__(256) void convH_k(
    const int* __restrict__ flag, int b,
    const bf16* __restrict__ in48, const float* __restrict__ wf,
    const float* __restrict__ stats, const T* __restrict__ gamma,
    const T* __restrict__ beta, bf16* __restrict__ out48, float* __restrict__ st)
{
  if (*flag != want_flag<T>::v) return;
  __shared__ float tile[4][342];
  __shared__ float sred[8][2];
  __shared__ float sc[HID], of[HID];
  int x0 = blockIdx.x * 16, y0 = blockIdx.y * 16;
  int tid = threadIdx.x;
  int tx = tid & 15, ty = tid >> 4;
  if (tid < 16) ((float*)sred)[tid] = 0.f;
  if (tid < HID) {
    int g = tid / 6;
    const float inv_n = 1.f / (6.f * HWP);
    float s  = stats[(b*8+g)*2+0];
    float s2 = stats[(b*8+g)*2+1];
    float m  = s * inv_n;
    float var = s2 * inv_n - m*m;
    float rs = rsqrtf(fmaxf(var, 0.f) + 1e-5f);
    float gm = ld(gamma, tid), bt = ld(beta, tid);
    sc[tid] = rs * gm;
    of[tid] = bt - m * rs * gm;
  }
  float acc[HID];
  #pragma unroll
  for (int i = 0; i < HID; ++i) acc[i] = 0.f;
  for (int c0 = 0; c0 < HID; c0 += 4) {
    __syncthreads();
    for (int i = tid; i < 4*324; i += 256) {
      int cc = i / 324; int rem = i - cc*324;
      int r = rem / 18; int cl = rem - r*18;
      int gy = y0 - 1 + r, gx = x0 - 1 + cl;
      float v = 0.f;
      if (gy >= 0 && gy < Hd && gx >= 0 && gx < Wd) {
        int c = c0 + cc;
        float raw = b2f(in48[(long)c*HWP + (long)gy*Wd + gx]);
        raw = raw * sc[c] + of[c];
        v = raw / (1.f + __expf(-raw));   // SiLU; zero-pad stays 0
      }
      tile[cc][r*19 + cl] = v;
    }
    __syncthreads();
    #pragma unroll
    for (int cc = 0; cc < 4; ++cc) {
      float v[9];
      #pragma unroll
      for (int dr = 0; dr < 3; ++dr)
        #pragma unroll
        for (int dc = 0; dc < 3; ++dc)
          v[dr*3+dc] = tile[cc][(ty+dr)*19 + (tx+dc)];
      const float* wp = wf + (long)(c0+cc)*HID*9;
      #pragma unroll
      for (int oc = 0; oc < HID; ++oc) {
        float a = acc[oc];
        #pragma unroll
        for (int k = 0; k < 9; ++k) a += wp[oc*9+k] * v[k];
        acc[oc] = a;
      }
    }
  }
  long obase = (long)(y0+ty)*Wd + (x0+tx);
  #pragma unroll
  for (int oc = 0; oc < HID; ++oc) out48[obase + (long)oc*HWP] = f2b(acc[oc]);
  gn_epilogue(acc, sred, st, b, tid);
}

// ---------------- heads: GN3+SiLU fused, 20 1x1 dots, output transforms; one batch ----------------
template<typename T>
__global__ __launch_bounds__(256) void heads_k(
    const int* __restrict__ flag, int b,
    const bf16* __restrict__ h48, const float* __restrict__ st,
    const T* __restrict__ gamma, const T* __restrict__ beta,
    const float* __restrict__ wh, const float* __restrict__ bh,
    const T* __restrict__ dP, const T* __restrict__ sxP, const T* __restrict__ syP,
    const T* __restrict__ featP, const T* __restrict__ confP,
    T* __restrict__ out)
{
  if (*flag != want_flag<T>::v) return;
  __shared__ float sc[HID], of[HID];
  int p = blockIdx.x * 256 + threadIdx.x;      // 0..HWP-1
  long idx = (long)b*HWP + p;
  if (threadIdx.x < HID) {
    int c = threadIdx.x;
    int g = c / 6;
    const float inv_n = 1.f / (6.f * HWP);
    float s  = st[(b*8+g)*2+0];
    float s2 = st[(b*8+g)*2+1];
    float m  = s * inv_n;
    float var = s2 * inv_n - m*m;
    float rs = rsqrtf(fmaxf(var, 0.f) + 1e-5f);
    float gm = ld(gamma, c), bt = ld(beta, c);
    sc[c] = rs * gm;
    of[c] = bt - m * rs * gm;
  }
  __syncthreads();
  float hv[HID];
  #pragma unroll
  for (int c = 0; c < HID; ++c) {
    float v = b2f(h48[(long)c*HWP + p]);
    v = v * sc[c] + of[c];
    hv[c] = v / (1.f + __expf(-v));
  }
  float dot[20];
  #pragma unroll
  for (int r = 0; r < 20; ++r) {
    float a = bh[r];
    #pragma unroll
    for (int c = 0; c < HID; ++c) a += wh[r*HID + c] * hv[c];
    dot[r] = a;
  }
  float dval = ld(dP, idx);
  float xd = dot[0] + dval;
  float sp = fmaxf(xd, 0.f) + log1pf(__expf(-fabsf(xd)));   // stable softplus
  stv(out, idx, sp);
  stv(out, NBHW + idx,    ld(sxP, idx) + 0.1f*dot[1]);
  stv(out, 2L*NBHW + idx, ld(syP, idx) + 0.1f*dot[2]);
  float cf = dot[3] + 2.f*ld(confP, idx) - 1.f;
  stv(out, 19L*NBHW + idx, 1.f/(1.f + __expf(-cf)));
  #pragma unroll
  for (int r = 0; r < 16; ++r) {
    long fi = ((long)(b*16 + r))*HWP + p;
    stv(out, 3L*NBHW + fi, ld(featP, fi) + dot[4+r]);
  }
}

extern "C" void kernel_launch(void* const* d_in, const int* in_sizes, int n_in,
                              void* d_out, int out_size, void* d_ws, size_t ws_size,
                              hipStream_t stream)
{
  // workspace layout: ~39.7 MB + flag
  char* ws = (char*)d_ws;
  size_t off = 0;
  bf16* h1 = (bf16*)(ws + off); off += (size_t)HID*HWP*sizeof(bf16);   // 19.66 MB
  bf16* h2 = (bf16*)(ws + off); off += (size_t)HID*HWP*sizeof(bf16);   // 19.66 MB
  float* wf1 = (float*)(ws + off); off += (size_t)NCH1*HID*9*sizeof(float);
  float* wf2 = (float*)(ws + off); off += (size_t)HID*HID*9*sizeof(float);
  float* wf3 = (float*)(ws + off); off += (size_t)HID*HID*9*sizeof(float);
  float* wh  = (float*)(ws + off); off += (size_t)20*HID*sizeof(float);
  float* bh  = (float*)(ws + off); off += 32*sizeof(float);
  float* st  = (float*)(ws + off); off += 96*sizeof(float);            // 3 layers x 16 x {sum,sumsq}
  int*   flag = (int*)(ws + off);  off += sizeof(int);

  hipMemsetAsync(st, 0, 96*sizeof(float), stream);
  probe_k<<<1, 256, 0, stream>>>((const unsigned short*)d_in[0], flag);

  dim3 cgrid(Wd/16, Hd/16, 1);

  #define LAUNCH_ALL(T) do { \
    const T* dP    = (const T*)d_in[0]; \
    const T* sxP   = (const T*)d_in[1]; \
    const T* syP   = (const T*)d_in[2]; \
    const T* featP = (const T*)d_in[3]; \
    const T* confP = (const T*)d_in[4]; \
    const T* fL    = (const T*)d_in[5]; \
    const T* fR    = (const T*)d_in[6]; \
    wconv_k<T><<<320, 256, 0, stream>>>(flag, (const T*)d_in[7], (const T*)d_in[8], \
        (const T*)d_in[9], (const T*)d_in[16], (const T*)d_in[17], (const T*)d_in[18], \
        (const T*)d_in[19], (const T*)d_in[20], (const T*)d_in[21], (const T*)d_in[22], \
        (const T*)d_in[23], (const T*)d_in[24], (const T*)d_in[25], wf1, wf2, wf3, wh, bh); \
    for (int b = 0; b < Bn; ++b) { \
      conv1f_k<T><<<cgrid, 256, 0, stream>>>(flag, b, fL, fR, featP, dP, sxP, syP, confP, wf1, h1, st + 0); \
      convH_k<T><<<cgrid, 256, 0, stream>>>(flag, b, h1, wf2, st + 0,  (const T*)d_in[10], (const T*)d_in[11], h2, st + 32); \
      convH_k<T><<<cgrid, 256, 0, stream>>>(flag, b, h2, wf3, st + 32, (const T*)d_in[12], (const T*)d_in[13], h1, st + 64); \
      heads_k<T><<<HWP/256, 256, 0, stream>>>(flag, b, h1, st + 64, (const T*)d_in[14], (const T*)d_in[15], \
          wh, bh, dP, sxP, syP, featP, confP, (T*)d_out); \
    } \
  } while (0)

  LAUNCH_ALL(bf16);
  LAUNCH_ALL(float);
  #undef LAUNCH_ALL
}

// Round 5
// 1132.708 us; speedup vs baseline: 2.9093x; 2.9093x over previous
//
#include <hip/hip_runtime.h>
#include <hip/hip_bf16.h>

typedef __hip_bfloat16 bf16;
typedef unsigned short u16;
typedef short v8s __attribute__((ext_vector_type(8)));
typedef u16   v8u __attribute__((ext_vector_type(8)));
typedef float v4f __attribute__((ext_vector_type(4)));

#define Hd 320
#define Wd 640
#define HWP (Hd*Wd)      // 204800
#define Bn 2
#define NCH1 188
#define HID 48
#define NBHW (Bn*HWP)    // 409600
#define CP 40            // LDS channel pitch (bf16 elems) per pixel (16B-aligned)
#define NPIX 324         // 18*18 halo pixels

static __device__ __forceinline__ float b2f(bf16 v){ return __bfloat162float(v); }
static __device__ __forceinline__ bf16  f2b(float v){ return __float2bfloat16(v); }
static __device__ __forceinline__ u16 f2u(float v){ bf16 t = f2b(v); return *reinterpret_cast<u16*>(&t); }
static __device__ __forceinline__ float u2f(u16 u){ return __uint_as_float(((unsigned)u) << 16); }

// templated external-buffer load/store
template<typename T> static __device__ __forceinline__ float ld(const T* p, long i);
template<> __device__ __forceinline__ float ld<bf16>(const bf16* p, long i){ return b2f(p[i]); }
template<> __device__ __forceinline__ float ld<float>(const float* p, long i){ return p[i]; }
template<typename T> static __device__ __forceinline__ void stv(T* p, long i, float v);
template<> __device__ __forceinline__ void stv<bf16>(bf16* p, long i, float v){ p[i] = f2b(v); }
template<> __device__ __forceinline__ void stv<float>(float* p, long i, float v){ p[i] = v; }
template<typename T> struct want_flag;           // 0 = bf16, 1 = f32
template<> struct want_flag<bf16>  { static const int v = 0; };
template<> struct want_flag<float> { static const int v = 1; };

// ---------------- dtype probe (proven in round 4) ----------------
__global__ void probe_k(const u16* __restrict__ dq, int* __restrict__ flag)
{
  __shared__ int cnt;
  if (threadIdx.x == 0) cnt = 0;
  __syncthreads();
  int bad = 0;
  for (int i = threadIdx.x; i < 2048; i += 256) {
    float v = __uint_as_float(((unsigned)dq[2*i]) << 16);
    if (!(fabsf(v) <= 65.f)) bad++;
  }
  atomicAdd(&cnt, bad);
  __syncthreads();
  if (threadIdx.x == 0) *flag = (cnt > 64) ? 1 : 0;
}

// ---------------- weight prepack: OIHW -> MFMA B-fragment order (bf16 bits) ----------------
// wf index: ((((chunk*9+tap)*3+nt)*64 + lane)*8 + j
// value = W[oc = nt*16 + (lane&15)][cin = chunk*32 + (lane>>4)*8 + j][tap]
template<typename T>
__global__ void wconv_k(const int* __restrict__ flag,
                        const T* __restrict__ c1, const T* __restrict__ c2,
                        const T* __restrict__ c3,
                        const T* __restrict__ hdw, const T* __restrict__ hdb,
                        const T* __restrict__ hsxw, const T* __restrict__ hsxb,
                        const T* __restrict__ hsyw, const T* __restrict__ hsyb,
                        const T* __restrict__ hcw,  const T* __restrict__ hcb,
                        const T* __restrict__ hfw,  const T* __restrict__ hfb,
                        u16* __restrict__ wf1, u16* __restrict__ wf2,
                        u16* __restrict__ wf3, float* __restrict__ wh,
                        float* __restrict__ bh)
{
  if (*flag != want_flag<T>::v) return;
  int stride = gridDim.x * blockDim.x;
  int t0 = blockIdx.x * blockDim.x + threadIdx.x;
  const int N1 = 6*9*3*64*8;     // 82944
  for (int idx = t0; idx < N1; idx += stride) {
    int j = idx & 7; int lane = (idx >> 3) & 63; int rest = idx >> 9;
    int nt = rest % 3; rest /= 3; int tap = rest % 9; int chunk = rest / 9;
    int oc = nt*16 + (lane & 15);
    int cin = chunk*32 + (lane >> 4)*8 + j;
    float v = (cin < NCH1) ? ld(c1, ((long)oc*NCH1 + cin)*9 + tap) : 0.f;
    wf1[idx] = f2u(v);
  }
  const int N2 = 2*9*3*64*8;     // 27648
  for (int idx = t0; idx < N2; idx += stride) {
    int j = idx & 7; int lane = (idx >> 3) & 63; int rest = idx >> 9;
    int nt = rest % 3; rest /= 3; int tap = rest % 9; int chunk = rest / 9;
    int oc = nt*16 + (lane & 15);
    int cin = chunk*32 + (lane >> 4)*8 + j;
    float v2 = 0.f, v3 = 0.f;
    if (cin < HID) {
      v2 = ld(c2, ((long)oc*HID + cin)*9 + tap);
      v3 = ld(c3, ((long)oc*HID + cin)*9 + tap);
    }
    wf2[idx] = f2u(v2);
    wf3[idx] = f2u(v3);
  }
  for (int i = t0; i < HID; i += stride) {
    wh[0*HID + i] = ld(hdw, i);
    wh[1*HID + i] = ld(hsxw, i);
    wh[2*HID + i] = ld(hsyw, i);
    wh[3*HID + i] = ld(hcw, i);
  }
  for (int i = t0; i < 16*HID; i += stride) wh[4*HID + i] = ld(hfw, i);
  if (t0 == 0) {
    bh[0] = ld(hdb,0); bh[1] = ld(hsxb,0); bh[2] = ld(hsyb,0); bh[3] = ld(hcb,0);
    for (int j = 0; j < 16; ++j) bh[4+j] = ld(hfb, j);
  }
}

// ---------------- warp + group-corr -> xc (bf16, 104 computed channels, one batch) ----------------
// xc ch 0..63 = fR warped by d; ch 64..103 = cost (g*5 + i5)
template<typename T>
__global__ __launch_bounds__(256) void build_x_k(
    const int* __restrict__ flag, int b,
    const T* __restrict__ dP, const T* __restrict__ fL, const T* __restrict__ fR,
    u16* __restrict__ xc)
{
  if (*flag != want_flag<T>::v) return;
  __shared__ float rowR[8][Wd];
  __shared__ float drow[Wd];
  int y = blockIdx.x;
  int tid = threadIdx.x;
  long rowoff = (long)y*Wd;
  for (int x = tid; x < Wd; x += 256) drow[x] = ld(dP, (long)b*HWP + rowoff + x);

  for (int g = 0; g < 8; ++g) {
    __syncthreads();
    for (int i = tid; i < 8*Wd; i += 256) {
      int cc = i / Wd, x = i - cc*Wd;
      rowR[cc][x] = ld(fR, ((long)(b*64 + g*8 + cc))*HWP + rowoff + x);
    }
    __syncthreads();
    for (int pi = 0; pi < 3; ++pi) {
      int x = tid + pi*256;
      if (x < Wd) {
        float base = (float)x - drow[x];
        float a0=0.f,a1=0.f,a2=0.f,a3=0.f,a4=0.f;
        #pragma unroll
        for (int cc = 0; cc < 8; ++cc) {
          int c = g*8 + cc;
          float fl = ld(fL, ((long)(b*64+c))*HWP + rowoff + x);
          float s[5];
          #pragma unroll
          for (int i5 = 0; i5 < 5; ++i5) {
            float pos = base - (float)(i5 - 2);
            pos = fminf(fmaxf(pos, 0.f), (float)(Wd-1));
            float x0f = floorf(pos);
            float w = pos - x0f;
            int i0 = (int)x0f;
            int i1 = min(i0 + 1, Wd-1);
            s[i5] = rowR[cc][i0] * (1.f - w) + rowR[cc][i1] * w;
          }
          a0 += fl*s[0]; a1 += fl*s[1]; a2 += fl*s[2]; a3 += fl*s[3]; a4 += fl*s[4];
          xc[(long)c*HWP + rowoff + x] = f2u(s[2]);    // warp == off=0 sample
        }
        long cb = (long)(64 + g*5)*HWP + rowoff + x;
        xc[cb]          = f2u(a0*0.125f);
        xc[cb + HWP]    = f2u(a1*0.125f);
        xc[cb + 2L*HWP] = f2u(a2*0.125f);
        xc[cb + 3L*HWP] = f2u(a3*0.125f);
        xc[cb + 4L*HWP] = f2u(a4*0.125f);
      }
    }
  }
}

// ---------------- shared conv epilogue: GN stats + coalesced bf16 store ----------------
static __device__ __forceinline__ void conv_epilogue(
    v4f (*acc)[3], u16* lds, float (*sred)[2], u16* out48,
    float* st, int b, int x0, int y0, int tid)
{
  int lane = tid & 63, wave = tid >> 6;
  // per-oc sums over this wave's 16 pixels, then quad-reduce
  #pragma unroll
  for (int nt = 0; nt < 3; ++nt) {
    float s = 0.f, s2 = 0.f;
    #pragma unroll
    for (int mi = 0; mi < 4; ++mi)
      #pragma unroll
      for (int r = 0; r < 4; ++r) { float v = acc[mi][nt][r]; s += v; s2 += v*v; }
    s  += __shfl_xor(s, 16);  s2 += __shfl_xor(s2, 16);
    s  += __shfl_xor(s, 32);  s2 += __shfl_xor(s2, 32);
    if (lane < 16) {
      int g = (nt*16 + lane) / 6;
      atomicAdd(&sred[g][0], s);
      atomicAdd(&sred[g][1], s2);
    }
  }
  __syncthreads();   // all LDS mfma reads done; safe to repurpose lds
  #pragma unroll
  for (int mi = 0; mi < 4; ++mi) {
    int py = wave*4 + mi;
    #pragma unroll
    for (int nt = 0; nt < 3; ++nt) {
      int oc = nt*16 + (lane & 15);
      #pragma unroll
      for (int r = 0; r < 4; ++r) {
        int px = (lane >> 4)*4 + r;                 // D: row = quad*4+reg
        lds[oc*270 + py*16 + px] = f2u(acc[mi][nt][r]);
      }
    }
  }
  __syncthreads();
  for (int i = tid; i < 48*256; i += 256) {
    int oc = i >> 8, pix = i & 255;
    out48[(long)oc*HWP + (long)(y0 + (pix>>4))*Wd + x0 + (pix&15)] = lds[oc*270 + pix];
  }
  if (tid < 16) atomicAdd(&st[(b*8 + (tid>>1))*2 + (tid&1)], sred[tid>>1][tid&1]);
}

// ---------------- conv1 MFMA: 188(+4 pad)ch gather -> 48, one batch ----------------
template<typename T>
__global__ __launch_bounds__(256) void conv1m_k(
    const int* __restrict__ flag, int b,
    const T* __restrict__ fL, const T* __restrict__ feat,
    const T* __restrict__ dP, const T* __restrict__ sxP, const T* __restrict__ syP,
    const T* __restrict__ confP, const u16* __restrict__ xcb,
    const u16* __restrict__ wfrag, u16* __restrict__ out48, float* __restrict__ st)
{
  if (*flag != want_flag<T>::v) return;
  __shared__ __attribute__((aligned(16))) u16 lds[12960];   // [324 px][pitch 40] / epilogue [48][270]
  __shared__ float sred[8][2];
  int x0 = blockIdx.x*16, y0 = blockIdx.y*16;
  int tid = threadIdx.x, lane = tid & 63, wave = tid >> 6;
  if (tid < 16) ((float*)sred)[tid] = 0.f;
  const T* fLb = fL + (long)b*64*HWP;
  v4f acc[4][3];
  #pragma unroll
  for (int mi = 0; mi < 4; ++mi)
    #pragma unroll
    for (int nt = 0; nt < 3; ++nt) acc[mi][nt] = (v4f){0.f,0.f,0.f,0.f};

  for (int ch = 0; ch < 6; ++ch) {
    int cb = ch*32;
    __syncthreads();
    // stage 32 channels x 324 halo pixels (8 channels per thread-iter, b128 LDS writes)
    for (int j = tid; j < 4*NPIX; j += 256) {
      int cq = j / NPIX, pix = j - cq*NPIX;
      int r = pix / 18, cl = pix - r*18;
      int gy = y0 - 1 + r, gx = x0 - 1 + cl;
      bool inb = (gy >= 0) & (gy < Hd) & (gx >= 0) & (gx < Wd);
      long rowb = (long)gy*Wd + gx;
      v8u vals;
      #pragma unroll
      for (int jj = 0; jj < 8; ++jj) {
        int c = cb + cq*8 + jj;
        float v = 0.f;
        if (inb) {
          if (c < 64)        v = ld(fLb, (long)c*HWP + rowb);
          else if (c < 128)  v = u2f(xcb[(long)(c-64)*HWP + rowb]);
          else if (c < 144)  v = ld(feat, (long)(b*16 + c-128)*HWP + rowb);
          else if (c == 144) v = ld(dP,   (long)b*HWP + rowb);
          else if (c == 145) v = ld(sxP,  (long)b*HWP + rowb);
          else if (c == 146) v = ld(syP,  (long)b*HWP + rowb);
          else if (c == 147) v = ld(confP,(long)b*HWP + rowb);
          else if (c < NCH1) v = u2f(xcb[(long)(64 + c-148)*HWP + rowb]);
        }
        vals[jj] = f2u(v);
      }
      *(v8u*)&lds[pix*CP + cq*8] = vals;
    }
    __syncthreads();
    #pragma unroll
    for (int tap = 0; tap < 9; ++tap) {
      int dr = tap / 3, dc = tap - dr*3;
      v8s bf0 = *(const v8s*)&wfrag[((((ch*9+tap)*3 + 0)*64 + lane) << 3)];
      v8s bf1 = *(const v8s*)&wfrag[((((ch*9+tap)*3 + 1)*64 + lane) << 3)];
      v8s bf2 = *(const v8s*)&wfrag[((((ch*9+tap)*3 + 2)*64 + lane) << 3)];
      #pragma unroll
      for (int mi = 0; mi < 4; ++mi) {
        int py = wave*4 + mi;
        const v8s a = *(const v8s*)&lds[((py+dr)*18 + (lane&15) + dc)*CP + (lane>>4)*8];
        acc[mi][0] = __builtin_amdgcn_mfma_f32_16x16x32_bf16(a, bf0, acc[mi][0], 0, 0, 0);
        acc[mi][1] = __builtin_amdgcn_mfma_f32_16x16x32_bf16(a, bf1, acc[mi][1], 0, 0, 0);
        acc[mi][2] = __builtin_amdgcn_mfma_f32_16x16x32_bf16(a, bf2, acc[mi][2], 0, 0, 0);
      }
    }
  }
  __syncthreads();
  conv_epilogue(acc, lds, sred, out48, st, b, x0, y0, tid);
}

// ---------------- convH MFMA: 48ch (GN+SiLU fused in staging) -> 48, one batch ----------------
template<typename T>
__global__ __launch_bounds__(256) void convHm_k(
    const int* __restrict__ flag, int b,
    const u16* __restrict__ in48, const u16* __restrict__ wfrag,
    const float* __restrict__ stats, const T* __restrict__ gamma,
    const T* __restrict__ beta, u16* __restrict__ out48, float* __restrict__ st)
{
  if (*flag != want_flag<T>::v) return;
  __shared__ __attribute__((aligned(16))) u16 lds[12960];
  __shared__ float sred[8][2];
  __shared__ float sc[HID], of[HID];
  int x0 = blockIdx.x*16, y0 = blockIdx.y*16;
  int tid = threadIdx.x, lane = tid & 63, wave = tid >> 6;
  if (tid < 16) ((float*)sred)[tid] = 0.f;
  if (tid < HID) {
    int g = tid / 6;
    const float inv_n = 1.f / (6.f * HWP);
    float s  = stats[(b*8+g)*2+0];
    float s2 = stats[(b*8+g)*2+1];
    float m  = s * inv_n;
    float var = s2 * inv_n - m*m;
    float rs = rsqrtf(fmaxf(var, 0.f) + 1e-5f);
    float gm = ld(gamma, tid), bt = ld(beta, tid);
    sc[tid] = rs * gm;
    of[tid] = bt - m * rs * gm;
  }
  v4f acc[4][3];
  #pragma unroll
  for (int mi = 0; mi < 4; ++mi)
    #pragma unroll
    for (int nt = 0; nt < 3; ++nt) acc[mi][nt] = (v4f){0.f,0.f,0.f,0.f};

  for (int ch = 0; ch < 2; ++ch) {
    int cb = ch*32;
    __syncthreads();
    for (int j = tid; j < 4*NPIX; j += 256) {
      int cq = j / NPIX, pix = j - cq*NPIX;
      int r = pix / 18, cl = pix - r*18;
      int gy = y0 - 1 + r, gx = x0 - 1 + cl;
      bool inb = (gy >= 0) & (gy < Hd) & (gx >= 0) & (gx < Wd);
      long rowb = (long)gy*Wd + gx;
      v8u vals;
      #pragma unroll
      for (int jj = 0; jj < 8; ++jj) {
        int c = cb + cq*8 + jj;
        float v = 0.f;
        if (inb && c < HID) {
          float raw = u2f(in48[(long)c*HWP + rowb]);
          raw = raw * sc[c] + of[c];
          v = raw / (1.f + __expf(-raw));       // SiLU; spatial zero-pad stays 0
        }
        vals[jj] = f2u(v);
      }
      *(v8u*)&lds[pix*CP + cq*8] = vals;
    }
    __syncthreads();
    #pragma unroll
    for (int tap = 0; tap < 9; ++tap) {
      int dr = tap / 3, dc = tap - dr*3;
      v8s bf0 = *(const v8s*)&wfrag[((((ch*9+tap)*3 + 0)*64 + lane) << 3)];
      v8s bf1 = *(const v8s*)&wfrag[((((ch*9+tap)*3 + 1)*64 + lane) << 3)];
      v8s bf2 = *(const v8s*)&wfrag[((((ch*9+tap)*3 + 2)*64 + lane) << 3)];
      #pragma unroll
      for (int mi = 0; mi < 4; ++mi) {
        int py = wave*4 + mi;
        const v8s a = *(const v8s*)&lds[((py+dr)*18 + (lane&15) + dc)*CP + (lane>>4)*8];
        acc[mi][0] = __builtin_amdgcn_mfma_f32_16x16x32_bf16(a, bf0, acc[mi][0], 0, 0, 0);
        acc[mi][1] = __builtin_amdgcn_mfma_f32_16x16x32_bf16(a, bf1, acc[mi][1], 0, 0, 0);
        acc[mi][2] = __builtin_amdgcn_mfma_f32_16x16x32_bf16(a, bf2, acc[mi][2], 0, 0, 0);
      }
    }
  }
  __syncthreads();
  conv_epilogue(acc, lds, sred, out48, st, b, x0, y0, tid);
}

// ---------------- heads: GN3+SiLU fused, 20 1x1 dots, output transforms; one batch ----------------
template<typename T>
__global__ __launch_bounds__(256) void heads_k(
    const int* __restrict__ flag, int b,
    const u16* __restrict__ h48, const float* __restrict__ st,
    const T* __restrict__ gamma, const T* __restrict__ beta,
    const float* __restrict__ wh, const float* __restrict__ bh,
    const T* __restrict__ dP, const T* __restrict__ sxP, const T* __restrict__ syP,
    const T* __restrict__ featP, const T* __restrict__ confP,
    T* __restrict__ out)
{
  if (*flag != want_flag<T>::v) return;
  __shared__ float sc[HID], of[HID];
  int p = blockIdx.x * 256 + threadIdx.x;
  long idx = (long)b*HWP + p;
  if (threadIdx.x < HID) {
    int c = threadIdx.x;
    int g = c / 6;
    const float inv_n = 1.f / (6.f * HWP);
    float s  = st[(b*8+g)*2+0];
    float s2 = st[(b*8+g)*2+1];
    float m  = s * inv_n;
    float var = s2 * inv_n - m*m;
    float rs = rsqrtf(fmaxf(var, 0.f) + 1e-5f);
    float gm = ld(gamma, c), bt = ld(beta, c);
    sc[c] = rs * gm;
    of[c] = bt - m * rs * gm;
  }
  __syncthreads();
  float hv[HID];
  #pragma unroll
  for (int c = 0; c < HID; ++c) {
    float v = u2f(h48[(long)c*HWP + p]);
    v = v * sc[c] + of[c];
    hv[c] = v / (1.f + __expf(-v));
  }
  float dot[20];
  #pragma unroll
  for (int r = 0; r < 20; ++r) {
    float a = bh[r];
    #pragma unroll
    for (int c = 0; c < HID; ++c) a += wh[r*HID + c] * hv[c];
    dot[r] = a;
  }
  float dval = ld(dP, idx);
  float xd = dot[0] + dval;
  float sp = fmaxf(xd, 0.f) + log1pf(__expf(-fabsf(xd)));
  stv(out, idx, sp);
  stv(out, NBHW + idx,    ld(sxP, idx) + 0.1f*dot[1]);
  stv(out, 2L*NBHW + idx, ld(syP, idx) + 0.1f*dot[2]);
  float cf = dot[3] + 2.f*ld(confP, idx) - 1.f;
  stv(out, 19L*NBHW + idx, 1.f/(1.f + __expf(-cf)));
  #pragma unroll
  for (int r = 0; r < 16; ++r) {
    long fi = ((long)(b*16 + r))*HWP + p;
    stv(out, 3L*NBHW + fi, ld(featP, fi) + dot[4+r]);
  }
}

extern "C" void kernel_launch(void* const* d_in, const int* in_sizes, int n_in,
                              void* d_out, int out_size, void* d_ws, size_t ws_size,
                              hipStream_t stream)
{
  // workspace (~59.6 MiB): xc shares memory with h2 (disjoint lifetimes)
  char* ws = (char*)d_ws;
  size_t off = 0;
  u16* xc  = (u16*)(ws + off); off += (size_t)104*HWP*sizeof(u16);  // 42.6 MB (xc, later h2)
  u16* h1  = (u16*)(ws + off); off += (size_t)HID*HWP*sizeof(u16);  // 19.66 MB (h1, later h3)
  u16* wf1 = (u16*)(ws + off); off += (size_t)6*9*3*64*8*sizeof(u16);
  u16* wf2 = (u16*)(ws + off); off += (size_t)2*9*3*64*8*sizeof(u16);
  u16* wf3 = (u16*)(ws + off); off += (size_t)2*9*3*64*8*sizeof(u16);
  float* wh = (float*)(ws + off); off += (size_t)20*HID*sizeof(float);
  float* bh = (float*)(ws + off); off += 32*sizeof(float);
  float* st = (float*)(ws + off); off += 96*sizeof(float);
  int* flag = (int*)(ws + off);   off += sizeof(int);
  u16* h2 = xc;     // reuse: xc dead after conv1 of each batch
  u16* h3 = h1;     // reuse: h1 dead after conv2

  hipMemsetAsync(st, 0, 96*sizeof(float), stream);
  probe_k<<<1, 256, 0, stream>>>((const u16*)d_in[0], flag);

  dim3 cgrid(Wd/16, Hd/16, 1);

  #define LAUNCH_ALL(T) do { \
    const T* dP    = (const T*)d_in[0]; \
    const T* sxP   = (const T*)d_in[1]; \
    const T* syP   = (const T*)d_in[2]; \
    const T* featP = (const T*)d_in[3]; \
    const T* confP = (const T*)d_in[4]; \
    const T* fL    = (const T*)d_in[5]; \
    const T* fR    = (const T*)d_in[6]; \
    wconv_k<T><<<320, 256, 0, stream>>>(flag, (const T*)d_in[7], (const T*)d_in[8], \
        (const T*)d_in[9], (const T*)d_in[16], (const T*)d_in[17], (const T*)d_in[18], \
        (const T*)d_in[19], (const T*)d_in[20], (const T*)d_in[21], (const T*)d_in[22], \
        (const T*)d_in[23], (const T*)d_in[24], (const T*)d_in[25], wf1, wf2, wf3, wh, bh); \
    for (int b = 0; b < Bn; ++b) { \
      build_x_k<T><<<Hd, 256, 0, stream>>>(flag, b, dP, fL, fR, xc); \
      conv1m_k<T><<<cgrid, 256, 0, stream>>>(flag, b, fL, featP, dP, sxP, syP, confP, xc, wf1, h1, st + 0); \
      convHm_k<T><<<cgrid, 256, 0, stream>>>(flag, b, h1, wf2, st + 0,  (const T*)d_in[10], (const T*)d_in[11], h2, st + 32); \
      convHm_k<T><<<cgrid, 256, 0, stream>>>(flag, b, h2, wf3, st + 32, (const T*)d_in[12], (const T*)d_in[13], h3, st + 64); \
      heads_k<T><<<HWP/256, 256, 0, stream>>>(flag, b, h3, st + 64, (const T*)d_in[14], (const T*)d_in[15], \
          wh, bh, dP, sxP, syP, featP, confP, (T*)d_out); \
    } \
  } while (0)

  LAUNCH_ALL(bf16);
  LAUNCH_ALL(float);
  #undef LAUNCH_ALL
}